// Round 10
// baseline (553.451 us; speedup 1.0000x reference)
//
#include <hip/hip_runtime.h>
#include <hip/hip_bf16.h>

#define N_NODES 50000
#define N_EDGES 800000
#define NPATH 3
#define NBKT 196                    // ceil(50000/256) buckets per path
#define NBKT3 (NPATH * NBKT)        // 588
#define NCHUNKBLK 256               // blocks for count/scatter passes
#define CHUNK 9375                  // (3*800000)/256 exact
#define A_STR 264                   // shorts per A-row in LDS (528B: 16B-aligned, <=2-way banks)

typedef __attribute__((ext_vector_type(8))) short short8;
typedef __attribute__((ext_vector_type(4))) float v4f;
typedef __attribute__((ext_vector_type(2))) float f2;
typedef __attribute__((ext_vector_type(4))) unsigned u32x4;  // nt-loadable uint4

// RNE f32 -> bf16 bits, also returns the rounded-back float.
__device__ __forceinline__ short f2bf(float v, float* back) {
  unsigned u = __float_as_uint(v);
  unsigned r = (u + 0x7FFFu + ((u >> 16) & 1u)) >> 16;
  *back = __uint_as_float(r << 16);
  return (short)r;
}

// unpack dword of 2 bf16 -> float2 {lo, hi}
__device__ __forceinline__ f2 up2(unsigned u) {
  f2 r;
  r.x = __uint_as_float(u << 16);
  r.y = __uint_as_float(u & 0xFFFF0000u);
  return r;
}

// ---------------------------------------------------------------------------
// CSR build passes A-E (unchanged; zero global atomics).
// ---------------------------------------------------------------------------
__global__ __launch_bounds__(256) void blk_count_kernel(
    const int* __restrict__ ei, int* __restrict__ cntmat) {
  __shared__ int lcnt[NBKT3];
  const int t = threadIdx.x, blk = blockIdx.x;
  for (int j = t; j < NBKT3; j += 256) lcnt[j] = 0;
  __syncthreads();
  const int lo = blk * CHUNK, hi = lo + CHUNK;
  for (int idx = lo + t; idx < hi; idx += 256) {
    int p = idx / N_EDGES, e = idx - p * N_EDGES;
    int d = ei[p * 2 * N_EDGES + N_EDGES + e];
    atomicAdd(&lcnt[p * NBKT + (d >> 8)], 1);   // LDS atomic
  }
  __syncthreads();
  for (int j = t; j < NBKT3; j += 256) cntmat[blk * NBKT3 + j] = lcnt[j];
}

__global__ __launch_bounds__(256) void col_scan_kernel(
    const int* __restrict__ cntmat, int* __restrict__ pos, int* __restrict__ btot) {
  __shared__ int tmp[256];
  const int b = blockIdx.x, t = threadIdx.x;
  int v = cntmat[t * NBKT3 + b];
  tmp[t] = v;
  __syncthreads();
  for (int ofs = 1; ofs < 256; ofs <<= 1) {
    int x = (t >= ofs) ? tmp[t - ofs] : 0;
    __syncthreads();
    tmp[t] += x;
    __syncthreads();
  }
  pos[b * 256 + t] = tmp[t] - v;
  if (t == 255) btot[b] = tmp[255];
}

__global__ __launch_bounds__(1024) void bucket_scan_kernel(
    const int* __restrict__ btot, int* __restrict__ boff) {
  __shared__ int tmp[1024];
  const int t = threadIdx.x;
  int v = (t < NBKT3) ? btot[t] : 0;
  tmp[t] = v;
  __syncthreads();
  for (int ofs = 1; ofs < 1024; ofs <<= 1) {
    int x = (t >= ofs) ? tmp[t - ofs] : 0;
    __syncthreads();
    tmp[t] += x;
    __syncthreads();
  }
  if (t < NBKT3) boff[t] = tmp[t] - v;
}

__global__ __launch_bounds__(256) void scatter_det_kernel(
    const int* __restrict__ ei, const int* __restrict__ boff,
    const int* __restrict__ pos, int2* __restrict__ ebuf) {
  __shared__ int cursor[NBKT3];
  const int t = threadIdx.x, blk = blockIdx.x;
  for (int j = t; j < NBKT3; j += 256)
    cursor[j] = boff[j] + pos[j * 256 + blk];
  __syncthreads();
  const int lo = blk * CHUNK, hi = lo + CHUNK;
  for (int idx = lo + t; idx < hi; idx += 256) {
    int p = idx / N_EDGES, e = idx - p * N_EDGES;
    int s = ei[p * 2 * N_EDGES + e];
    int d = ei[p * 2 * N_EDGES + N_EDGES + e];
    int ps = atomicAdd(&cursor[p * NBKT + (d >> 8)], 1);   // LDS atomic
    ebuf[ps] = make_int2(s, d);
  }
}

__global__ __launch_bounds__(256) void bucket_csr_kernel(
    const int2* __restrict__ ebuf, const int* __restrict__ boff,
    const int* __restrict__ btot,
    int* __restrict__ off3, int* __restrict__ deg3, int* __restrict__ csr_src) {
  __shared__ int cnt[256], excl[256], cur[256];
  const int b = blockIdx.x;
  const int t = threadIdx.x;
  const int p = b / NBKT;
  const int node_base = (b - p * NBKT) * 256;
  const int start = boff[b];
  const int ecount = btot[b];

  cnt[t] = 0;
  __syncthreads();
  for (int i = t; i < ecount; i += 256)
    atomicAdd(&cnt[ebuf[start + i].y & 255], 1);
  __syncthreads();

  int v = cnt[t];
  excl[t] = v;
  __syncthreads();
  for (int ofs = 1; ofs < 256; ofs <<= 1) {
    int x = (t >= ofs) ? excl[t - ofs] : 0;
    __syncthreads();
    excl[t] += x;
    __syncthreads();
  }
  int my_excl = excl[t] - v;
  cur[t] = my_excl;
  const int node = node_base + t;
  if (node < N_NODES) {
    off3[p * N_NODES + node] = start + my_excl;   // GLOBAL offset
    deg3[p * N_NODES + node] = v;
  }
  __syncthreads();

  for (int i = t; i < ecount; i += 256) {
    int2 e = ebuf[start + i];
    int pos2 = atomicAdd(&cur[e.y & 255], 1);
    csr_src[start + pos2] = e.x;
  }
}

// ---------------------------------------------------------------------------
// Fused prep (all paths, one dispatch). Unchanged.
// ---------------------------------------------------------------------------
__global__ __launch_bounds__(256) void prep_kernel(
    const float* __restrict__ fc_w, const float* __restrict__ attn_l,
    const float* __restrict__ attn_r, const float* __restrict__ sem_w,
    __hip_bfloat16* __restrict__ Wf_hi, __hip_bfloat16* __restrict__ Wf_lo,
    __hip_bfloat16* __restrict__ Bs_hi, __hip_bfloat16* __restrict__ Bs_lo) {
  const int p = blockIdx.x / 33;
  const int unit = blockIdx.x % 33;
  const int t = threadIdx.x;
  if (unit < 17) {
    const float* W = fc_w + (size_t)p * 128 * 256;
    int idx = unit * 256 + t;        // < 4352 = 4*17*64
    int lane = idx & 63;
    int tmp = idx >> 6;              // kc*17 + nt
    int nt = tmp % 17, kc = tmp / 17;
    int l15 = lane & 15, quad = lane >> 4;
    __hip_bfloat16* oh = Wf_hi + (size_t)p * 34816;
    __hip_bfloat16* ol = Wf_lo + (size_t)p * 34816;
    for (int j = 0; j < 8; j++) {
      int k = kc * 32 + quad * 8 + j;
      float v;
      if (nt < 16) {
        v = W[k * 256 + nt * 16 + l15];
      } else {
        int h8 = l15 & 7;
        const float* av = ((l15 < 8) ? attn_l : attn_r) + (size_t)p * 256 + h8 * 32;
        v = 0.f;
        for (int dd = 0; dd < 32; dd++)
          v = fmaf(W[k * 256 + h8 * 32 + dd], av[dd], v);
      }
      float back, back2;
      short hb = f2bf(v, &back);
      short lb = f2bf(v - back, &back2);
      ((short*)oh)[(tmp * 64 + lane) * 8 + j] = hb;
      ((short*)ol)[(tmp * 64 + lane) * 8 + j] = lb;
    }
  } else {
    const float* Ws = sem_w + (size_t)p * 256 * 128;
    int idx = (unit - 17) * 256 + t; // < 4096 = 8*8*64
    int lane = idx & 63;
    int tmp = idx >> 6;              // kc*8 + nt
    int nt = tmp & 7, kc = tmp >> 3;
    int l15 = lane & 15, quad = lane >> 4;
    __hip_bfloat16* oh = Bs_hi + (size_t)p * 32768;
    __hip_bfloat16* ol = Bs_lo + (size_t)p * 32768;
    for (int j = 0; j < 8; j++) {
      int k = kc * 32 + quad * 8 + j;
      float v = Ws[k * 128 + nt * 16 + l15];
      float back, back2;
      short hb = f2bf(v, &back);
      short lb = f2bf(v - back, &back2);
      ((short*)oh)[(tmp * 64 + lane) * 8 + j] = hb;
      ((short*)ol)[(tmp * 64 + lane) * 8 + j] = lb;
    }
  }
}

// ---------------------------------------------------------------------------
// MFMA 1: all 3 paths in one dispatch, grid.y = p. Unchanged.
// ---------------------------------------------------------------------------
__global__ __launch_bounds__(64) void feat_mfma_kernel(
    const float* __restrict__ h,
    const __hip_bfloat16* __restrict__ Wf_hi_all,
    const __hip_bfloat16* __restrict__ Wf_lo_all,
    __hip_bfloat16* __restrict__ feat3, float* __restrict__ el3,
    float* __restrict__ er3) {
  const int p = blockIdx.y;
  const __hip_bfloat16* Wf_hi = Wf_hi_all + (size_t)p * 34816;
  const __hip_bfloat16* Wf_lo = Wf_lo_all + (size_t)p * 34816;
  __hip_bfloat16* feat = feat3 + (size_t)p * N_NODES * 256;
  float* el = el3 + (size_t)p * N_NODES * 8;
  float* er = er3 + (size_t)p * N_NODES * 8;

  const int lane = threadIdx.x;
  const int l15 = lane & 15, quad = lane >> 4;
  const int m0 = blockIdx.x * 16;
  const int mrow = m0 + l15;

  v4f acc[17];
#pragma unroll
  for (int nt = 0; nt < 17; nt++) acc[nt] = {0.f, 0.f, 0.f, 0.f};

#pragma unroll
  for (int kc = 0; kc < 4; kc++) {
    const float* hrow = h + (size_t)mrow * 128 + kc * 32 + quad * 8;
    float4 fa = *(const float4*)hrow;
    float4 fb = *(const float4*)(hrow + 4);
    float fv[8] = {fa.x, fa.y, fa.z, fa.w, fb.x, fb.y, fb.z, fb.w};
    short8 ahi, alo;
#pragma unroll
    for (int q = 0; q < 8; q++) {
      float back, back2;
      ahi[q] = f2bf(fv[q], &back);
      alo[q] = f2bf(fv[q] - back, &back2);
    }
#pragma unroll
    for (int nt = 0; nt < 17; nt++) {
      const int o = ((kc * 17 + nt) * 64 + lane) * 8;
      short8 bhi = *(const short8*)(Wf_hi + o);
      short8 blo = *(const short8*)(Wf_lo + o);
      acc[nt] = __builtin_amdgcn_mfma_f32_16x16x32_bf16(ahi, bhi, acc[nt], 0, 0, 0);
      acc[nt] = __builtin_amdgcn_mfma_f32_16x16x32_bf16(ahi, blo, acc[nt], 0, 0, 0);
      acc[nt] = __builtin_amdgcn_mfma_f32_16x16x32_bf16(alo, bhi, acc[nt], 0, 0, 0);
    }
  }

#pragma unroll
  for (int nt = 0; nt < 16; nt++)
#pragma unroll
    for (int r = 0; r < 4; r++) {
      int m = m0 + quad * 4 + r;
      feat[(size_t)m * 256 + nt * 16 + l15] = __float2bfloat16(acc[nt][r]);
    }
#pragma unroll
  for (int r = 0; r < 4; r++) {
    int m = m0 + quad * 4 + r;
    float v = acc[16][r];
    if (l15 < 8) el[m * 8 + l15] = v;
    else         er[m * 8 + (l15 - 8)] = v;
  }
}

// ---------------------------------------------------------------------------
// R20 fused aggregate + semantic GEMM — R14 base (best: 241us) + NON-TEMPORAL
// gather loads (R19 resubmit; fixed: __builtin_nontemporal_load requires clang
// ext_vector types, not HIP_vector_type uint4 -> use u32x4).
// Evidence: clean configs plateau at 2.5-2.9 TB/s gather rate across all
// occupancy/ILP/VALU variations; Little's law puts ~36 cache lines in flight
// per CU = L1/TCP miss-queue depth. Spill runs proved TCC can do >4 TB/s.
// feat/el gathers have ~zero L1 reuse -> `nt` loads skip L1 allocation and
// its miss-tag bottleneck. csr_src/deg/off/Bs loads stay cached.
// ---------------------------------------------------------------------------
__global__ __launch_bounds__(512) void agg_sem_kernel(
    const int* __restrict__ csr_src, const int* __restrict__ off3,
    const int* __restrict__ deg3,
    const float* __restrict__ el3, const float* __restrict__ er3,
    const __hip_bfloat16* __restrict__ feat3,
    const __hip_bfloat16* __restrict__ Bs_hi, const __hip_bfloat16* __restrict__ Bs_lo,
    const float* __restrict__ bias, float* __restrict__ out) {
  __shared__ __align__(16) short Ahi[16 * A_STR];   // 8448 B
  __shared__ __align__(16) short Alo[16 * A_STR];   // 8448 B
  __shared__ int idxbuf[8 * 128];                   // 4096 B (2 nodes / wave)
  const int t = threadIdx.x;
  const int w = t >> 6, lane = t & 63;
  const int half = lane >> 5;          // 0: even edges, 1: odd edges
  const int l5 = lane & 31;            // channel group: channels 8*l5 .. 8*l5+7
  const int hh = l5 >> 2;              // head of this lane's 8 channels
  const int node_base = blockIdx.x * 16;
  const int l15 = lane & 15, quad = lane >> 4;
  const int nt = w;

  v4f acc = {0.f, 0.f, 0.f, 0.f};

  for (int p = 0; p < NPATH; p++) {
    const int* offp = off3 + p * N_NODES;
    const int* degp = deg3 + p * N_NODES;
    const float* elh = el3 + (size_t)p * N_NODES * 8 + hh;
    const float* erp = er3 + (size_t)p * N_NODES * 8;
    const ushort* fpl = (const ushort*)(feat3 + (size_t)p * N_NODES * 256) + l5 * 8;

    const int node0 = node_base + 2 * w;
    const int nA_deg = degp[node0];
    const int nB_deg = degp[node0 + 1];
    const int* LA = csr_src + offp[node0];
    const int* LB = csr_src + offp[node0 + 1];
    // stage both nodes' edge indices (lane (half,l5) -> edge 2*l5+half)
    {
      int pos = 2 * l5 + half;
      int sb = w * 128 + (half << 5) + l5;
      idxbuf[sb]      = (pos < nA_deg) ? LA[pos] : 0;
      idxbuf[sb + 64] = (pos < nB_deg) ? LB[pos] : 0;
    }

#define LD(S, kk) do {                                                    \
      int2 id_ = *(const int2*)&idxbuf[ib2 + (kk)];                       \
      unsigned ia_ = (unsigned)id_.x, ic_ = (unsigned)id_.y;              \
      x##S##a = __builtin_nontemporal_load(elh + ia_ * 8u);               \
      x##S##b = __builtin_nontemporal_load(elh + ic_ * 8u);               \
      f##S##a = __builtin_nontemporal_load((const u32x4*)(fpl + ia_ * 256u)); \
      f##S##b = __builtin_nontemporal_load((const u32x4*)(fpl + ic_ * 256u)); \
    } while (0)

#define CN(S, kk) do {                                                    \
      float xx0 = x##S##a + erh;                                          \
      xx0 = fmaxf(xx0, 0.2f * xx0);                                       \
      float e0 = ((kk) < nh) ? __expf(xx0) : 0.f;                         \
      float xx1 = x##S##b + erh;                                          \
      xx1 = fmaxf(xx1, 0.2f * xx1);                                       \
      float e1 = ((kk) + 1 < nh) ? __expf(xx1) : 0.f;                     \
      aD += e0; aD += e1;                                                 \
      f2 e20 = {e0, e0}, e21 = {e1, e1};                                  \
      a0 = __builtin_elementwise_fma(e20, up2(f##S##a.x), a0);            \
      a1 = __builtin_elementwise_fma(e20, up2(f##S##a.y), a1);            \
      a2 = __builtin_elementwise_fma(e20, up2(f##S##a.z), a2);            \
      a3 = __builtin_elementwise_fma(e20, up2(f##S##a.w), a3);            \
      a0 = __builtin_elementwise_fma(e21, up2(f##S##b.x), a0);            \
      a1 = __builtin_elementwise_fma(e21, up2(f##S##b.y), a1);            \
      a2 = __builtin_elementwise_fma(e21, up2(f##S##b.z), a2);            \
      a3 = __builtin_elementwise_fma(e21, up2(f##S##b.w), a3);            \
    } while (0)

    // ---- edge phase: wave w aggregates nodes 2w and 2w+1 ----
#pragma unroll
    for (int i = 0; i < 2; i++) {
      const int node = node0 + i;
      const int n = (i == 0) ? nA_deg : nB_deg;
      const int* lst2 = (i == 0) ? LA : LB;
      const float erh = erp[node * 8 + hh];
      const int ncov = n < 64 ? n : 64;
      const int nh = (ncov - half + 1) >> 1;   // valid edges this half
      const int nmax = (ncov + 1) >> 1;        // uniform loop bound
      const int ib2 = w * 128 + i * 64 + (half << 5);

      f2 a0 = {0.f, 0.f}, a1 = {0.f, 0.f}, a2 = {0.f, 0.f}, a3 = {0.f, 0.f};
      float aD = 0.f;
      u32x4 fAa, fAb, fBa, fBb, fCa, fCb;
      float xAa, xAb, xBa, xBb, xCa, xCb;

      if (nmax > 0) LD(A, 0);
      if (nmax > 2) LD(B, 2);
      if (nmax > 4) LD(C, 4);
      for (int k = 0; k < nmax; k += 6) {
        CN(A, k);
        if (k + 6 < nmax) LD(A, k + 6);
        if (k + 2 < nmax) {
          CN(B, k + 2);
          if (k + 8 < nmax) LD(B, k + 8);
          if (k + 4 < nmax) {
            CN(C, k + 4);
            if (k + 10 < nmax) LD(C, k + 10);
          }
        }
      }
      // rare tail: degree > 64 (~0 nodes for Poisson-16 degrees)
      if (n > 64) {
        for (int j = 64; j < n; j += 2) {
          int v = (j + half) < n;
          unsigned su = v ? (unsigned)lst2[j + half] : 0u;
          float x = __builtin_nontemporal_load(elh + su * 8u);
          u32x4 f = __builtin_nontemporal_load((const u32x4*)(fpl + su * 256u));
          float xx = x + erh;
          xx = fmaxf(xx, 0.2f * xx);
          float e = v ? __expf(xx) : 0.f;
          aD += e;
          f2 e2t = {e, e};
          a0 = __builtin_elementwise_fma(e2t, up2(f.x), a0);
          a1 = __builtin_elementwise_fma(e2t, up2(f.y), a1);
          a2 = __builtin_elementwise_fma(e2t, up2(f.z), a2);
          a3 = __builtin_elementwise_fma(e2t, up2(f.w), a3);
        }
      }

      // combine even/odd halves (lane l <-> lane l+32)
      float aN[8] = {a0.x, a0.y, a1.x, a1.y, a2.x, a2.y, a3.x, a3.y};
#pragma unroll
      for (int k = 0; k < 8; k++) aN[k] += __shfl_xor(aN[k], 32, 64);
      aD += __shfl_xor(aD, 32, 64);

      float inv = (n > 0) ? 1.f / aD : 0.f;
      // ELU + hi/lo bf16 split ONCE, store fragment-ready
      short8 hi8, lo8;
#pragma unroll
      for (int k = 0; k < 8; k++) {
        float r = aN[k] * inv;
        r = r > 0.f ? r : (__expf(r) - 1.f);
        float back, back2;
        hi8[k] = f2bf(r, &back);
        lo8[k] = f2bf(r - back, &back2);
      }
      const int row = 2 * w + i;
      short* dst = half ? Alo : Ahi;
      short8 vv = half ? lo8 : hi8;
      *(short8*)&dst[row * A_STR + l5 * 8] = vv;
    }
#undef LD
#undef CN
    __syncthreads();

    // ---- sem MFMA phase: wave w -> N-tile nt = w; acc accumulates over p ----
    const __hip_bfloat16* bh = Bs_hi + (size_t)p * 32768;
    const __hip_bfloat16* bl = Bs_lo + (size_t)p * 32768;
#pragma unroll
    for (int kc = 0; kc < 8; kc++) {
      short8 ahi = *(const short8*)&Ahi[l15 * A_STR + kc * 32 + quad * 8];
      short8 alo = *(const short8*)&Alo[l15 * A_STR + kc * 32 + quad * 8];
      const int o = ((kc * 8 + nt) * 64 + lane) * 8;
      short8 bhi = *(const short8*)(bh + o);
      short8 blo = *(const short8*)(bl + o);
      acc = __builtin_amdgcn_mfma_f32_16x16x32_bf16(ahi, bhi, acc, 0, 0, 0);
      acc = __builtin_amdgcn_mfma_f32_16x16x32_bf16(ahi, blo, acc, 0, 0, 0);
      acc = __builtin_amdgcn_mfma_f32_16x16x32_bf16(alo, bhi, acc, 0, 0, 0);
    }
    __syncthreads();   // protect LDS before next path overwrites
  }

  const float bv = bias[nt * 16 + l15];
#pragma unroll
  for (int r = 0; r < 4; r++) {
    int m = node_base + quad * 4 + r;
    out[(size_t)m * 128 + nt * 16 + l15] = acc[r] + bv;
  }
}

// ---------------------------------------------------------------------------
extern "C" void kernel_launch(void* const* d_in, const int* in_sizes, int n_in,
                              void* d_out, int out_size, void* d_ws, size_t ws_size,
                              hipStream_t stream) {
  const float* h      = (const float*)d_in[0];
  const int*   ei     = (const int*)d_in[1];
  const float* fc_w   = (const float*)d_in[2];
  const float* attn_l = (const float*)d_in[3];
  const float* attn_r = (const float*)d_in[4];
  const float* sem_w  = (const float*)d_in[5];
  const float* sem_b  = (const float*)d_in[6];
  float* out = (float*)d_out;

  // workspace layout (bytes) — total ~118.4 MB (<=132.8 MB proven safe)
  char* ws = (char*)d_ws;
  __hip_bfloat16* feat3 = (__hip_bfloat16*)ws;                     // 76.8 MB
  float* el3     = (float*)(ws + 76800000);                        // 4.8 MB
  float* er3     = (float*)(ws + 81600000);                        // 4.8 MB
  int*   csr_src = (int*)(ws + 86400000);                          // 9.6 MB
  int2*  ebuf    = (int2*)(ws + 96000000);                         // 19.2 MB
  int*   deg3    = (int*)(ws + 115200000);                         // 0.6 MB
  int*   off3    = (int*)(ws + 115800000);                         // 0.6 MB
  int*   cntmat  = (int*)(ws + 116400000);                         // 602 KB
  int*   posm    = (int*)(ws + 117050000);                         // 602 KB
  int*   btot    = (int*)(ws + 117700000);                         // 2.4 KB
  int*   boff    = (int*)(ws + 117710000);                         // 2.4 KB
  __hip_bfloat16* Wf_hi = (__hip_bfloat16*)(ws + 117800000);       // 3x69632 B
  __hip_bfloat16* Wf_lo = (__hip_bfloat16*)(ws + 118050000);       // 3x69632 B
  __hip_bfloat16* Bs_hi = (__hip_bfloat16*)(ws + 118300000);       // 3x65536 B
  __hip_bfloat16* Bs_lo = (__hip_bfloat16*)(ws + 118550000);       // 3x65536 B

  // --- CSR build (deterministic counting sort) + fused weight prep ---
  blk_count_kernel<<<NCHUNKBLK, 256, 0, stream>>>(ei, cntmat);
  col_scan_kernel<<<NBKT3, 256, 0, stream>>>(cntmat, posm, btot);
  bucket_scan_kernel<<<1, 1024, 0, stream>>>(btot, boff);
  scatter_det_kernel<<<NCHUNKBLK, 256, 0, stream>>>(ei, boff, posm, ebuf);
  bucket_csr_kernel<<<NBKT3, 256, 0, stream>>>(ebuf, boff, btot, off3, deg3, csr_src);
  prep_kernel<<<NPATH * 33, 256, 0, stream>>>(fc_w, attn_l, attn_r, sem_w,
                                              Wf_hi, Wf_lo, Bs_hi, Bs_lo);

  // --- all 3 feat GEMMs in one dispatch ---
  feat_mfma_kernel<<<dim3(N_NODES / 16, NPATH), 64, 0, stream>>>(
      h, Wf_hi, Wf_lo, feat3, el3, er3);

  // --- fused aggregate + semantic GEMM, all 3 paths in ONE dispatch ---
  agg_sem_kernel<<<N_NODES / 16, 512, 0, stream>>>(
      csr_src, off3, deg3, el3, er3, feat3, Bs_hi, Bs_lo, sem_b, out);
}

// Round 11
// 491.147 us; speedup vs baseline: 1.1269x; 1.1269x over previous
//
#include <hip/hip_runtime.h>
#include <hip/hip_bf16.h>

#define N_NODES 50000
#define N_EDGES 800000
#define NPATH 3
#define NBKT 196                    // ceil(50000/256) buckets per path
#define NBKT3 (NPATH * NBKT)        // 588
#define NCHUNKBLK 256               // blocks for count/scatter passes
#define CHUNK 9375                  // (3*800000)/256 exact
#define A_STR 264                   // shorts per A-row in LDS (528B: 16B-aligned, <=2-way banks)

typedef __attribute__((ext_vector_type(8))) short short8;
typedef __attribute__((ext_vector_type(4))) float v4f;
typedef __attribute__((ext_vector_type(2))) float f2;

// RNE f32 -> bf16 bits, also returns the rounded-back float.
__device__ __forceinline__ short f2bf(float v, float* back) {
  unsigned u = __float_as_uint(v);
  unsigned r = (u + 0x7FFFu + ((u >> 16) & 1u)) >> 16;
  *back = __uint_as_float(r << 16);
  return (short)r;
}

// unpack dword of 2 bf16 -> float2 {lo, hi}
__device__ __forceinline__ f2 up2(unsigned u) {
  f2 r;
  r.x = __uint_as_float(u << 16);
  r.y = __uint_as_float(u & 0xFFFF0000u);
  return r;
}

// ---------------------------------------------------------------------------
// CSR build passes A-E. R21: cntmat stored TRANSPOSED [bucket][chunk] so
// col_scan reads are coalesced (was stride-2352B column reads).
// ---------------------------------------------------------------------------
__global__ __launch_bounds__(256) void blk_count_kernel(
    const int* __restrict__ ei, int* __restrict__ cntmat) {
  __shared__ int lcnt[NBKT3];
  const int t = threadIdx.x, blk = blockIdx.x;
  for (int j = t; j < NBKT3; j += 256) lcnt[j] = 0;
  __syncthreads();
  const int lo = blk * CHUNK, hi = lo + CHUNK;
  for (int idx = lo + t; idx < hi; idx += 256) {
    int p = idx / N_EDGES, e = idx - p * N_EDGES;
    int d = ei[p * 2 * N_EDGES + N_EDGES + e];
    atomicAdd(&lcnt[p * NBKT + (d >> 8)], 1);   // LDS atomic
  }
  __syncthreads();
  for (int j = t; j < NBKT3; j += 256)
    cntmat[j * NCHUNKBLK + blk] = lcnt[j];      // transposed write
}

__global__ __launch_bounds__(256) void col_scan_kernel(
    const int* __restrict__ cntmat, int* __restrict__ pos, int* __restrict__ btot) {
  __shared__ int tmp[256];
  const int b = blockIdx.x, t = threadIdx.x;
  int v = cntmat[b * NCHUNKBLK + t];            // coalesced read
  tmp[t] = v;
  __syncthreads();
  for (int ofs = 1; ofs < 256; ofs <<= 1) {
    int x = (t >= ofs) ? tmp[t - ofs] : 0;
    __syncthreads();
    tmp[t] += x;
    __syncthreads();
  }
  pos[b * 256 + t] = tmp[t] - v;
  if (t == 255) btot[b] = tmp[255];
}

__global__ __launch_bounds__(1024) void bucket_scan_kernel(
    const int* __restrict__ btot, int* __restrict__ boff) {
  __shared__ int tmp[1024];
  const int t = threadIdx.x;
  int v = (t < NBKT3) ? btot[t] : 0;
  tmp[t] = v;
  __syncthreads();
  for (int ofs = 1; ofs < 1024; ofs <<= 1) {
    int x = (t >= ofs) ? tmp[t - ofs] : 0;
    __syncthreads();
    tmp[t] += x;
    __syncthreads();
  }
  if (t < NBKT3) boff[t] = tmp[t] - v;
}

__global__ __launch_bounds__(256) void scatter_det_kernel(
    const int* __restrict__ ei, const int* __restrict__ boff,
    const int* __restrict__ pos, int2* __restrict__ ebuf) {
  __shared__ int cursor[NBKT3];
  const int t = threadIdx.x, blk = blockIdx.x;
  for (int j = t; j < NBKT3; j += 256)
    cursor[j] = boff[j] + pos[j * 256 + blk];
  __syncthreads();
  const int lo = blk * CHUNK, hi = lo + CHUNK;
  for (int idx = lo + t; idx < hi; idx += 256) {
    int p = idx / N_EDGES, e = idx - p * N_EDGES;
    int s = ei[p * 2 * N_EDGES + e];
    int d = ei[p * 2 * N_EDGES + N_EDGES + e];
    int ps = atomicAdd(&cursor[p * NBKT + (d >> 8)], 1);   // LDS atomic
    ebuf[ps] = make_int2(s, d);
  }
}

__global__ __launch_bounds__(256) void bucket_csr_kernel(
    const int2* __restrict__ ebuf, const int* __restrict__ boff,
    const int* __restrict__ btot,
    int* __restrict__ off3, int* __restrict__ deg3, int* __restrict__ csr_src) {
  __shared__ int cnt[256], excl[256], cur[256];
  const int b = blockIdx.x;
  const int t = threadIdx.x;
  const int p = b / NBKT;
  const int node_base = (b - p * NBKT) * 256;
  const int start = boff[b];
  const int ecount = btot[b];

  cnt[t] = 0;
  __syncthreads();
  for (int i = t; i < ecount; i += 256)
    atomicAdd(&cnt[ebuf[start + i].y & 255], 1);
  __syncthreads();

  int v = cnt[t];
  excl[t] = v;
  __syncthreads();
  for (int ofs = 1; ofs < 256; ofs <<= 1) {
    int x = (t >= ofs) ? excl[t - ofs] : 0;
    __syncthreads();
    excl[t] += x;
    __syncthreads();
  }
  int my_excl = excl[t] - v;
  cur[t] = my_excl;
  const int node = node_base + t;
  if (node < N_NODES) {
    off3[p * N_NODES + node] = start + my_excl;   // GLOBAL offset
    deg3[p * N_NODES + node] = v;
  }
  __syncthreads();

  for (int i = t; i < ecount; i += 256) {
    int2 e = ebuf[start + i];
    int pos2 = atomicAdd(&cur[e.y & 255], 1);
    csr_src[start + pos2] = e.x;
  }
}

// ---------------------------------------------------------------------------
// Fused prep (all paths, one dispatch). Unchanged.
// ---------------------------------------------------------------------------
__global__ __launch_bounds__(256) void prep_kernel(
    const float* __restrict__ fc_w, const float* __restrict__ attn_l,
    const float* __restrict__ attn_r, const float* __restrict__ sem_w,
    __hip_bfloat16* __restrict__ Wf_hi, __hip_bfloat16* __restrict__ Wf_lo,
    __hip_bfloat16* __restrict__ Bs_hi, __hip_bfloat16* __restrict__ Bs_lo) {
  const int p = blockIdx.x / 33;
  const int unit = blockIdx.x % 33;
  const int t = threadIdx.x;
  if (unit < 17) {
    const float* W = fc_w + (size_t)p * 128 * 256;
    int idx = unit * 256 + t;        // < 4352 = 4*17*64
    int lane = idx & 63;
    int tmp = idx >> 6;              // kc*17 + nt
    int nt = tmp % 17, kc = tmp / 17;
    int l15 = lane & 15, quad = lane >> 4;
    __hip_bfloat16* oh = Wf_hi + (size_t)p * 34816;
    __hip_bfloat16* ol = Wf_lo + (size_t)p * 34816;
    for (int j = 0; j < 8; j++) {
      int k = kc * 32 + quad * 8 + j;
      float v;
      if (nt < 16) {
        v = W[k * 256 + nt * 16 + l15];
      } else {
        int h8 = l15 & 7;
        const float* av = ((l15 < 8) ? attn_l : attn_r) + (size_t)p * 256 + h8 * 32;
        v = 0.f;
        for (int dd = 0; dd < 32; dd++)
          v = fmaf(W[k * 256 + h8 * 32 + dd], av[dd], v);
      }
      float back, back2;
      short hb = f2bf(v, &back);
      short lb = f2bf(v - back, &back2);
      ((short*)oh)[(tmp * 64 + lane) * 8 + j] = hb;
      ((short*)ol)[(tmp * 64 + lane) * 8 + j] = lb;
    }
  } else {
    const float* Ws = sem_w + (size_t)p * 256 * 128;
    int idx = (unit - 17) * 256 + t; // < 4096 = 8*8*64
    int lane = idx & 63;
    int tmp = idx >> 6;              // kc*8 + nt
    int nt = tmp & 7, kc = tmp >> 3;
    int l15 = lane & 15, quad = lane >> 4;
    __hip_bfloat16* oh = Bs_hi + (size_t)p * 32768;
    __hip_bfloat16* ol = Bs_lo + (size_t)p * 32768;
    for (int j = 0; j < 8; j++) {
      int k = kc * 32 + quad * 8 + j;
      float v = Ws[k * 128 + nt * 16 + l15];
      float back, back2;
      short hb = f2bf(v, &back);
      short lb = f2bf(v - back, &back2);
      ((short*)oh)[(tmp * 64 + lane) * 8 + j] = hb;
      ((short*)ol)[(tmp * 64 + lane) * 8 + j] = lb;
    }
  }
}

// ---------------------------------------------------------------------------
// MFMA 1 — R21: feat stores vectorized via per-block LDS bounce.
// Was: 64 scalar 2B global stores per lane (76.8MB at 2B/lane/instr).
// Now: scalar ds_write_b16 into an 8.4KB tile buffer (<=2-way banks), then
// 8x short8 coalesced stores (half-wave covers each 512B row exactly).
// ---------------------------------------------------------------------------
__global__ __launch_bounds__(64) void feat_mfma_kernel(
    const float* __restrict__ h,
    const __hip_bfloat16* __restrict__ Wf_hi_all,
    const __hip_bfloat16* __restrict__ Wf_lo_all,
    __hip_bfloat16* __restrict__ feat3, float* __restrict__ el3,
    float* __restrict__ er3) {
  __shared__ __align__(16) short Sbuf[16 * A_STR];   // 8448 B
  const int p = blockIdx.y;
  const __hip_bfloat16* Wf_hi = Wf_hi_all + (size_t)p * 34816;
  const __hip_bfloat16* Wf_lo = Wf_lo_all + (size_t)p * 34816;
  __hip_bfloat16* feat = feat3 + (size_t)p * N_NODES * 256;
  float* el = el3 + (size_t)p * N_NODES * 8;
  float* er = er3 + (size_t)p * N_NODES * 8;

  const int lane = threadIdx.x;
  const int l15 = lane & 15, quad = lane >> 4;
  const int m0 = blockIdx.x * 16;
  const int mrow = m0 + l15;

  v4f acc[17];
#pragma unroll
  for (int nt = 0; nt < 17; nt++) acc[nt] = {0.f, 0.f, 0.f, 0.f};

#pragma unroll
  for (int kc = 0; kc < 4; kc++) {
    const float* hrow = h + (size_t)mrow * 128 + kc * 32 + quad * 8;
    float4 fa = *(const float4*)hrow;
    float4 fb = *(const float4*)(hrow + 4);
    float fv[8] = {fa.x, fa.y, fa.z, fa.w, fb.x, fb.y, fb.z, fb.w};
    short8 ahi, alo;
#pragma unroll
    for (int q = 0; q < 8; q++) {
      float back, back2;
      ahi[q] = f2bf(fv[q], &back);
      alo[q] = f2bf(fv[q] - back, &back2);
    }
#pragma unroll
    for (int nt = 0; nt < 17; nt++) {
      const int o = ((kc * 17 + nt) * 64 + lane) * 8;
      short8 bhi = *(const short8*)(Wf_hi + o);
      short8 blo = *(const short8*)(Wf_lo + o);
      acc[nt] = __builtin_amdgcn_mfma_f32_16x16x32_bf16(ahi, bhi, acc[nt], 0, 0, 0);
      acc[nt] = __builtin_amdgcn_mfma_f32_16x16x32_bf16(ahi, blo, acc[nt], 0, 0, 0);
      acc[nt] = __builtin_amdgcn_mfma_f32_16x16x32_bf16(alo, bhi, acc[nt], 0, 0, 0);
    }
  }

  // stage tile to LDS (scalar b16 writes, cheap), then coalesced 16B stores
#pragma unroll
  for (int nt = 0; nt < 16; nt++)
#pragma unroll
    for (int r = 0; r < 4; r++) {
      float back;
      Sbuf[(quad * 4 + r) * A_STR + nt * 16 + l15] = f2bf(acc[nt][r], &back);
    }
  // single wave: compiler orders ds_write -> ds_read via lgkmcnt
#pragma unroll
  for (int q = 0; q < 8; q++) {
    int rr = q * 2 + (lane >> 5);
    int cs = (lane & 31) * 8;
    short8 v = *(const short8*)&Sbuf[rr * A_STR + cs];
    *(short8*)((short*)feat + (size_t)(m0 + rr) * 256 + cs) = v;
  }
#pragma unroll
  for (int r = 0; r < 4; r++) {
    int m = m0 + quad * 4 + r;
    float v = acc[16][r];
    if (l15 < 8) el[m * 8 + l15] = v;
    else         er[m * 8 + (l15 - 8)] = v;
  }
}

// ---------------------------------------------------------------------------
// R14 fused aggregate + semantic GEMM (EXACT revert — best measured: 241us).
// 512 thr, 8 waves, 2 nodes/wave, 3-stage A/B/C pipeline, pk-fma, all 3
// paths in one dispatch, sem MFMA nt=w. No nt-loads (R20 regression -44%).
// ---------------------------------------------------------------------------
__global__ __launch_bounds__(512) void agg_sem_kernel(
    const int* __restrict__ csr_src, const int* __restrict__ off3,
    const int* __restrict__ deg3,
    const float* __restrict__ el3, const float* __restrict__ er3,
    const __hip_bfloat16* __restrict__ feat3,
    const __hip_bfloat16* __restrict__ Bs_hi, const __hip_bfloat16* __restrict__ Bs_lo,
    const float* __restrict__ bias, float* __restrict__ out) {
  __shared__ __align__(16) short Ahi[16 * A_STR];   // 8448 B
  __shared__ __align__(16) short Alo[16 * A_STR];   // 8448 B
  __shared__ int idxbuf[8 * 128];                   // 4096 B (2 nodes / wave)
  const int t = threadIdx.x;
  const int w = t >> 6, lane = t & 63;
  const int half = lane >> 5;          // 0: even edges, 1: odd edges
  const int l5 = lane & 31;            // channel group: channels 8*l5 .. 8*l5+7
  const int hh = l5 >> 2;              // head of this lane's 8 channels
  const int node_base = blockIdx.x * 16;
  const int l15 = lane & 15, quad = lane >> 4;
  const int nt = w;

  v4f acc = {0.f, 0.f, 0.f, 0.f};

  for (int p = 0; p < NPATH; p++) {
    const int* offp = off3 + p * N_NODES;
    const int* degp = deg3 + p * N_NODES;
    const float* elh = el3 + (size_t)p * N_NODES * 8 + hh;
    const float* erp = er3 + (size_t)p * N_NODES * 8;
    const ushort* fpl = (const ushort*)(feat3 + (size_t)p * N_NODES * 256) + l5 * 8;

    const int node0 = node_base + 2 * w;
    const int nA_deg = degp[node0];
    const int nB_deg = degp[node0 + 1];
    const int* LA = csr_src + offp[node0];
    const int* LB = csr_src + offp[node0 + 1];
    // stage both nodes' edge indices (lane (half,l5) -> edge 2*l5+half)
    {
      int pos = 2 * l5 + half;
      int sb = w * 128 + (half << 5) + l5;
      idxbuf[sb]      = (pos < nA_deg) ? LA[pos] : 0;
      idxbuf[sb + 64] = (pos < nB_deg) ? LB[pos] : 0;
    }

#define LD(S, kk) do {                                                    \
      int2 id_ = *(const int2*)&idxbuf[ib2 + (kk)];                       \
      unsigned ia_ = (unsigned)id_.x, ic_ = (unsigned)id_.y;              \
      x##S##a = elh[ia_ * 8u];                                            \
      x##S##b = elh[ic_ * 8u];                                            \
      f##S##a = *(const uint4*)(fpl + ia_ * 256u);                        \
      f##S##b = *(const uint4*)(fpl + ic_ * 256u);                        \
    } while (0)

#define CN(S, kk) do {                                                    \
      float xx0 = x##S##a + erh;                                          \
      xx0 = fmaxf(xx0, 0.2f * xx0);                                       \
      float e0 = ((kk) < nh) ? __expf(xx0) : 0.f;                         \
      float xx1 = x##S##b + erh;                                          \
      xx1 = fmaxf(xx1, 0.2f * xx1);                                       \
      float e1 = ((kk) + 1 < nh) ? __expf(xx1) : 0.f;                     \
      aD += e0; aD += e1;                                                 \
      f2 e20 = {e0, e0}, e21 = {e1, e1};                                  \
      a0 = __builtin_elementwise_fma(e20, up2(f##S##a.x), a0);            \
      a1 = __builtin_elementwise_fma(e20, up2(f##S##a.y), a1);            \
      a2 = __builtin_elementwise_fma(e20, up2(f##S##a.z), a2);            \
      a3 = __builtin_elementwise_fma(e20, up2(f##S##a.w), a3);            \
      a0 = __builtin_elementwise_fma(e21, up2(f##S##b.x), a0);            \
      a1 = __builtin_elementwise_fma(e21, up2(f##S##b.y), a1);            \
      a2 = __builtin_elementwise_fma(e21, up2(f##S##b.z), a2);            \
      a3 = __builtin_elementwise_fma(e21, up2(f##S##b.w), a3);            \
    } while (0)

    // ---- edge phase: wave w aggregates nodes 2w and 2w+1 ----
#pragma unroll
    for (int i = 0; i < 2; i++) {
      const int node = node0 + i;
      const int n = (i == 0) ? nA_deg : nB_deg;
      const int* lst2 = (i == 0) ? LA : LB;
      const float erh = erp[node * 8 + hh];
      const int ncov = n < 64 ? n : 64;
      const int nh = (ncov - half + 1) >> 1;   // valid edges this half
      const int nmax = (ncov + 1) >> 1;        // uniform loop bound
      const int ib2 = w * 128 + i * 64 + (half << 5);

      f2 a0 = {0.f, 0.f}, a1 = {0.f, 0.f}, a2 = {0.f, 0.f}, a3 = {0.f, 0.f};
      float aD = 0.f;
      uint4 fAa, fAb, fBa, fBb, fCa, fCb;
      float xAa, xAb, xBa, xBb, xCa, xCb;

      if (nmax > 0) LD(A, 0);
      if (nmax > 2) LD(B, 2);
      if (nmax > 4) LD(C, 4);
      for (int k = 0; k < nmax; k += 6) {
        CN(A, k);
        if (k + 6 < nmax) LD(A, k + 6);
        if (k + 2 < nmax) {
          CN(B, k + 2);
          if (k + 8 < nmax) LD(B, k + 8);
          if (k + 4 < nmax) {
            CN(C, k + 4);
            if (k + 10 < nmax) LD(C, k + 10);
          }
        }
      }
      // rare tail: degree > 64 (~0 nodes for Poisson-16 degrees)
      if (n > 64) {
        for (int j = 64; j < n; j += 2) {
          int v = (j + half) < n;
          unsigned su = v ? (unsigned)lst2[j + half] : 0u;
          float x = elh[su * 8u];
          uint4 f = *(const uint4*)(fpl + su * 256u);
          float xx = x + erh;
          xx = fmaxf(xx, 0.2f * xx);
          float e = v ? __expf(xx) : 0.f;
          aD += e;
          f2 e2t = {e, e};
          a0 = __builtin_elementwise_fma(e2t, up2(f.x), a0);
          a1 = __builtin_elementwise_fma(e2t, up2(f.y), a1);
          a2 = __builtin_elementwise_fma(e2t, up2(f.z), a2);
          a3 = __builtin_elementwise_fma(e2t, up2(f.w), a3);
        }
      }

      // combine even/odd halves (lane l <-> lane l+32)
      float aN[8] = {a0.x, a0.y, a1.x, a1.y, a2.x, a2.y, a3.x, a3.y};
#pragma unroll
      for (int k = 0; k < 8; k++) aN[k] += __shfl_xor(aN[k], 32, 64);
      aD += __shfl_xor(aD, 32, 64);

      float inv = (n > 0) ? 1.f / aD : 0.f;
      // ELU + hi/lo bf16 split ONCE, store fragment-ready
      short8 hi8, lo8;
#pragma unroll
      for (int k = 0; k < 8; k++) {
        float r = aN[k] * inv;
        r = r > 0.f ? r : (__expf(r) - 1.f);
        float back, back2;
        hi8[k] = f2bf(r, &back);
        lo8[k] = f2bf(r - back, &back2);
      }
      const int row = 2 * w + i;
      short* dst = half ? Alo : Ahi;
      short8 vv = half ? lo8 : hi8;
      *(short8*)&dst[row * A_STR + l5 * 8] = vv;
    }
#undef LD
#undef CN
    __syncthreads();

    // ---- sem MFMA phase: wave w -> N-tile nt = w; acc accumulates over p ----
    const __hip_bfloat16* bh = Bs_hi + (size_t)p * 32768;
    const __hip_bfloat16* bl = Bs_lo + (size_t)p * 32768;
#pragma unroll
    for (int kc = 0; kc < 8; kc++) {
      short8 ahi = *(const short8*)&Ahi[l15 * A_STR + kc * 32 + quad * 8];
      short8 alo = *(const short8*)&Alo[l15 * A_STR + kc * 32 + quad * 8];
      const int o = ((kc * 8 + nt) * 64 + lane) * 8;
      short8 bhi = *(const short8*)(bh + o);
      short8 blo = *(const short8*)(bl + o);
      acc = __builtin_amdgcn_mfma_f32_16x16x32_bf16(ahi, bhi, acc, 0, 0, 0);
      acc = __builtin_amdgcn_mfma_f32_16x16x32_bf16(ahi, blo, acc, 0, 0, 0);
      acc = __builtin_amdgcn_mfma_f32_16x16x32_bf16(alo, bhi, acc, 0, 0, 0);
    }
    __syncthreads();   // protect LDS before next path overwrites
  }

  const float bv = bias[nt * 16 + l15];
#pragma unroll
  for (int r = 0; r < 4; r++) {
    int m = node_base + quad * 4 + r;
    out[(size_t)m * 128 + nt * 16 + l15] = acc[r] + bv;
  }
}

// ---------------------------------------------------------------------------
extern "C" void kernel_launch(void* const* d_in, const int* in_sizes, int n_in,
                              void* d_out, int out_size, void* d_ws, size_t ws_size,
                              hipStream_t stream) {
  const float* h      = (const float*)d_in[0];
  const int*   ei     = (const int*)d_in[1];
  const float* fc_w   = (const float*)d_in[2];
  const float* attn_l = (const float*)d_in[3];
  const float* attn_r = (const float*)d_in[4];
  const float* sem_w  = (const float*)d_in[5];
  const float* sem_b  = (const float*)d_in[6];
  float* out = (float*)d_out;

  // workspace layout (bytes) — total ~118.4 MB (<=132.8 MB proven safe)
  char* ws = (char*)d_ws;
  __hip_bfloat16* feat3 = (__hip_bfloat16*)ws;                     // 76.8 MB
  float* el3     = (float*)(ws + 76800000);                        // 4.8 MB
  float* er3     = (float*)(ws + 81600000);                        // 4.8 MB
  int*   csr_src = (int*)(ws + 86400000);                          // 9.6 MB
  int2*  ebuf    = (int2*)(ws + 96000000);                         // 19.2 MB
  int*   deg3    = (int*)(ws + 115200000);                         // 0.6 MB
  int*   off3    = (int*)(ws + 115800000);                         // 0.6 MB
  int*   cntmat  = (int*)(ws + 116400000);                         // 602 KB
  int*   posm    = (int*)(ws + 117050000);                         // 602 KB
  int*   btot    = (int*)(ws + 117700000);                         // 2.4 KB
  int*   boff    = (int*)(ws + 117710000);                         // 2.4 KB
  __hip_bfloat16* Wf_hi = (__hip_bfloat16*)(ws + 117800000);       // 3x69632 B
  __hip_bfloat16* Wf_lo = (__hip_bfloat16*)(ws + 118050000);       // 3x69632 B
  __hip_bfloat16* Bs_hi = (__hip_bfloat16*)(ws + 118300000);       // 3x65536 B
  __hip_bfloat16* Bs_lo = (__hip_bfloat16*)(ws + 118550000);       // 3x65536 B

  // --- CSR build (deterministic counting sort) + fused weight prep ---
  blk_count_kernel<<<NCHUNKBLK, 256, 0, stream>>>(ei, cntmat);
  col_scan_kernel<<<NBKT3, 256, 0, stream>>>(cntmat, posm, btot);
  bucket_scan_kernel<<<1, 1024, 0, stream>>>(btot, boff);
  scatter_det_kernel<<<NCHUNKBLK, 256, 0, stream>>>(ei, boff, posm, ebuf);
  bucket_csr_kernel<<<NBKT3, 256, 0, stream>>>(ebuf, boff, btot, off3, deg3, csr_src);
  prep_kernel<<<NPATH * 33, 256, 0, stream>>>(fc_w, attn_l, attn_r, sem_w,
                                              Wf_hi, Wf_lo, Bs_hi, Bs_lo);

  // --- all 3 feat GEMMs in one dispatch ---
  feat_mfma_kernel<<<dim3(N_NODES / 16, NPATH), 64, 0, stream>>>(
      h, Wf_hi, Wf_lo, feat3, el3, er3);

  // --- fused aggregate + semantic GEMM, all 3 paths in ONE dispatch ---
  agg_sem_kernel<<<N_NODES / 16, 512, 0, stream>>>(
      csr_src, off3, deg3, el3, er3, feat3, Bs_hi, Bs_lo, sem_b, out);
}

// Round 12
// 460.450 us; speedup vs baseline: 1.2020x; 1.0667x over previous
//
#include <hip/hip_runtime.h>
#include <hip/hip_bf16.h>

#define N_NODES 50000
#define N_EDGES 800000
#define NPATH 3
#define NBKT 196                    // ceil(50000/256) buckets per path
#define NBKT3 (NPATH * NBKT)        // 588
#define NCHUNKBLK 256               // blocks for count/scatter passes
#define CHUNK 9375                  // (3*800000)/256 exact
#define A_STR 264                   // shorts per A-row in LDS (528B: 16B-aligned, <=2-way banks)

typedef __attribute__((ext_vector_type(8))) short short8;
typedef __attribute__((ext_vector_type(4))) float v4f;
typedef __attribute__((ext_vector_type(2))) float f2;

// RNE f32 -> bf16 bits, also returns the rounded-back float.
__device__ __forceinline__ short f2bf(float v, float* back) {
  unsigned u = __float_as_uint(v);
  unsigned r = (u + 0x7FFFu + ((u >> 16) & 1u)) >> 16;
  *back = __uint_as_float(r << 16);
  return (short)r;
}

// unpack dword of 2 bf16 -> float2 {lo, hi}
__device__ __forceinline__ f2 up2(unsigned u) {
  f2 r;
  r.x = __uint_as_float(u << 16);
  r.y = __uint_as_float(u & 0xFFFF0000u);
  return r;
}

// ---------------------------------------------------------------------------
// CSR build passes A-E (exact R14; zero global atomics).
// ---------------------------------------------------------------------------
__global__ __launch_bounds__(256) void blk_count_kernel(
    const int* __restrict__ ei, int* __restrict__ cntmat) {
  __shared__ int lcnt[NBKT3];
  const int t = threadIdx.x, blk = blockIdx.x;
  for (int j = t; j < NBKT3; j += 256) lcnt[j] = 0;
  __syncthreads();
  const int lo = blk * CHUNK, hi = lo + CHUNK;
  for (int idx = lo + t; idx < hi; idx += 256) {
    int p = idx / N_EDGES, e = idx - p * N_EDGES;
    int d = ei[p * 2 * N_EDGES + N_EDGES + e];
    atomicAdd(&lcnt[p * NBKT + (d >> 8)], 1);   // LDS atomic
  }
  __syncthreads();
  for (int j = t; j < NBKT3; j += 256) cntmat[blk * NBKT3 + j] = lcnt[j];
}

__global__ __launch_bounds__(256) void col_scan_kernel(
    const int* __restrict__ cntmat, int* __restrict__ pos, int* __restrict__ btot) {
  __shared__ int tmp[256];
  const int b = blockIdx.x, t = threadIdx.x;
  int v = cntmat[t * NBKT3 + b];
  tmp[t] = v;
  __syncthreads();
  for (int ofs = 1; ofs < 256; ofs <<= 1) {
    int x = (t >= ofs) ? tmp[t - ofs] : 0;
    __syncthreads();
    tmp[t] += x;
    __syncthreads();
  }
  pos[b * 256 + t] = tmp[t] - v;
  if (t == 255) btot[b] = tmp[255];
}

__global__ __launch_bounds__(1024) void bucket_scan_kernel(
    const int* __restrict__ btot, int* __restrict__ boff) {
  __shared__ int tmp[1024];
  const int t = threadIdx.x;
  int v = (t < NBKT3) ? btot[t] : 0;
  tmp[t] = v;
  __syncthreads();
  for (int ofs = 1; ofs < 1024; ofs <<= 1) {
    int x = (t >= ofs) ? tmp[t - ofs] : 0;
    __syncthreads();
    tmp[t] += x;
    __syncthreads();
  }
  if (t < NBKT3) boff[t] = tmp[t] - v;
}

__global__ __launch_bounds__(256) void scatter_det_kernel(
    const int* __restrict__ ei, const int* __restrict__ boff,
    const int* __restrict__ pos, int2* __restrict__ ebuf) {
  __shared__ int cursor[NBKT3];
  const int t = threadIdx.x, blk = blockIdx.x;
  for (int j = t; j < NBKT3; j += 256)
    cursor[j] = boff[j] + pos[j * 256 + blk];
  __syncthreads();
  const int lo = blk * CHUNK, hi = lo + CHUNK;
  for (int idx = lo + t; idx < hi; idx += 256) {
    int p = idx / N_EDGES, e = idx - p * N_EDGES;
    int s = ei[p * 2 * N_EDGES + e];
    int d = ei[p * 2 * N_EDGES + N_EDGES + e];
    int ps = atomicAdd(&cursor[p * NBKT + (d >> 8)], 1);   // LDS atomic
    ebuf[ps] = make_int2(s, d);
  }
}

__global__ __launch_bounds__(256) void bucket_csr_kernel(
    const int2* __restrict__ ebuf, const int* __restrict__ boff,
    const int* __restrict__ btot,
    int* __restrict__ off3, int* __restrict__ deg3, int* __restrict__ csr_src) {
  __shared__ int cnt[256], excl[256], cur[256];
  const int b = blockIdx.x;
  const int t = threadIdx.x;
  const int p = b / NBKT;
  const int node_base = (b - p * NBKT) * 256;
  const int start = boff[b];
  const int ecount = btot[b];

  cnt[t] = 0;
  __syncthreads();
  for (int i = t; i < ecount; i += 256)
    atomicAdd(&cnt[ebuf[start + i].y & 255], 1);
  __syncthreads();

  int v = cnt[t];
  excl[t] = v;
  __syncthreads();
  for (int ofs = 1; ofs < 256; ofs <<= 1) {
    int x = (t >= ofs) ? excl[t - ofs] : 0;
    __syncthreads();
    excl[t] += x;
    __syncthreads();
  }
  int my_excl = excl[t] - v;
  cur[t] = my_excl;
  const int node = node_base + t;
  if (node < N_NODES) {
    off3[p * N_NODES + node] = start + my_excl;   // GLOBAL offset
    deg3[p * N_NODES + node] = v;
  }
  __syncthreads();

  for (int i = t; i < ecount; i += 256) {
    int2 e = ebuf[start + i];
    int pos2 = atomicAdd(&cur[e.y & 255], 1);
    csr_src[start + pos2] = e.x;
  }
}

// ---------------------------------------------------------------------------
// Fused prep (all paths, one dispatch). Unchanged.
// ---------------------------------------------------------------------------
__global__ __launch_bounds__(256) void prep_kernel(
    const float* __restrict__ fc_w, const float* __restrict__ attn_l,
    const float* __restrict__ attn_r, const float* __restrict__ sem_w,
    __hip_bfloat16* __restrict__ Wf_hi, __hip_bfloat16* __restrict__ Wf_lo,
    __hip_bfloat16* __restrict__ Bs_hi, __hip_bfloat16* __restrict__ Bs_lo) {
  const int p = blockIdx.x / 33;
  const int unit = blockIdx.x % 33;
  const int t = threadIdx.x;
  if (unit < 17) {
    const float* W = fc_w + (size_t)p * 128 * 256;
    int idx = unit * 256 + t;        // < 4352 = 4*17*64
    int lane = idx & 63;
    int tmp = idx >> 6;              // kc*17 + nt
    int nt = tmp % 17, kc = tmp / 17;
    int l15 = lane & 15, quad = lane >> 4;
    __hip_bfloat16* oh = Wf_hi + (size_t)p * 34816;
    __hip_bfloat16* ol = Wf_lo + (size_t)p * 34816;
    for (int j = 0; j < 8; j++) {
      int k = kc * 32 + quad * 8 + j;
      float v;
      if (nt < 16) {
        v = W[k * 256 + nt * 16 + l15];
      } else {
        int h8 = l15 & 7;
        const float* av = ((l15 < 8) ? attn_l : attn_r) + (size_t)p * 256 + h8 * 32;
        v = 0.f;
        for (int dd = 0; dd < 32; dd++)
          v = fmaf(W[k * 256 + h8 * 32 + dd], av[dd], v);
      }
      float back, back2;
      short hb = f2bf(v, &back);
      short lb = f2bf(v - back, &back2);
      ((short*)oh)[(tmp * 64 + lane) * 8 + j] = hb;
      ((short*)ol)[(tmp * 64 + lane) * 8 + j] = lb;
    }
  } else {
    const float* Ws = sem_w + (size_t)p * 256 * 128;
    int idx = (unit - 17) * 256 + t; // < 4096 = 8*8*64
    int lane = idx & 63;
    int tmp = idx >> 6;              // kc*8 + nt
    int nt = tmp & 7, kc = tmp >> 3;
    int l15 = lane & 15, quad = lane >> 4;
    __hip_bfloat16* oh = Bs_hi + (size_t)p * 32768;
    __hip_bfloat16* ol = Bs_lo + (size_t)p * 32768;
    for (int j = 0; j < 8; j++) {
      int k = kc * 32 + quad * 8 + j;
      float v = Ws[k * 128 + nt * 16 + l15];
      float back, back2;
      short hb = f2bf(v, &back);
      short lb = f2bf(v - back, &back2);
      ((short*)oh)[(tmp * 64 + lane) * 8 + j] = hb;
      ((short*)ol)[(tmp * 64 + lane) * 8 + j] = lb;
    }
  }
}

// ---------------------------------------------------------------------------
// MFMA 1 — R22: 4-wave blocks with LDS-staged weights.
// Old: 9375 1-wave blocks, each re-reading ALL Wf (136KB) from L2 -> 1.27GB
// of L2 weight traffic, latency-bound at 16 rows per weight byte.
// New: 256-thread blocks (wave w -> M-tile blk*64 + w*16); per kc the block
// cooperatively stages Whi/Wlo (34.8KB) into LDS with coalesced short8 loads,
// all 4 waves read fragments via ds_read_b128. Weight L2 traffic /4
// (326MB); 4 blocks/CU by LDS. Grid (782,3), row-guarded (50000 = 781*64+16).
// Stores: R14-style scalar (measured better than LDS-bounce in R21).
// ---------------------------------------------------------------------------
__global__ __launch_bounds__(256) void feat_mfma_kernel(
    const float* __restrict__ h,
    const __hip_bfloat16* __restrict__ Wf_hi_all,
    const __hip_bfloat16* __restrict__ Wf_lo_all,
    __hip_bfloat16* __restrict__ feat3, float* __restrict__ el3,
    float* __restrict__ er3) {
  __shared__ __align__(16) short Wh[17 * 64 * 8];   // 17408 B
  __shared__ __align__(16) short Wl[17 * 64 * 8];   // 17408 B
  const int p = blockIdx.y;
  const short8* Wf_hi = (const short8*)(Wf_hi_all + (size_t)p * 34816);
  const short8* Wf_lo = (const short8*)(Wf_lo_all + (size_t)p * 34816);
  __hip_bfloat16* feat = feat3 + (size_t)p * N_NODES * 256;
  float* el = el3 + (size_t)p * N_NODES * 8;
  float* er = er3 + (size_t)p * N_NODES * 8;

  const int t = threadIdx.x;
  const int w = t >> 6, lane = t & 63;
  const int l15 = lane & 15, quad = lane >> 4;
  const int m0 = blockIdx.x * 64 + w * 16;
  const int mrow = m0 + l15;
  const int mld = mrow < N_NODES ? mrow : N_NODES - 1;  // clamp (stores guarded)

  v4f acc[17];
#pragma unroll
  for (int nt = 0; nt < 17; nt++) acc[nt] = {0.f, 0.f, 0.f, 0.f};

  for (int kc = 0; kc < 4; kc++) {
    // ---- stage weights for this kc (coalesced; 2176 x 16B total) ----
    if (kc) __syncthreads();                  // protect prior reads
    {
      const short8* sh = Wf_hi + kc * 1088;   // 17*64*8 shorts = 1088 short8
      const short8* sl = Wf_lo + kc * 1088;
      short8* dh = (short8*)Wh;
      short8* dl = (short8*)Wl;
      for (int u = t; u < 1088; u += 256) dh[u] = sh[u];
      for (int u = t; u < 1088; u += 256) dl[u] = sl[u];
    }
    __syncthreads();

    // ---- a-frag from h ----
    const float* hrow = h + (size_t)mld * 128 + kc * 32 + quad * 8;
    float4 fa = *(const float4*)hrow;
    float4 fb = *(const float4*)(hrow + 4);
    float fv[8] = {fa.x, fa.y, fa.z, fa.w, fb.x, fb.y, fb.z, fb.w};
    short8 ahi, alo;
#pragma unroll
    for (int q = 0; q < 8; q++) {
      float back, back2;
      ahi[q] = f2bf(fv[q], &back);
      alo[q] = f2bf(fv[q] - back, &back2);
    }
    // ---- MFMA over 17 N-tiles, weights from LDS ----
#pragma unroll
    for (int nt = 0; nt < 17; nt++) {
      short8 bhi = ((const short8*)Wh)[nt * 64 + lane];
      short8 blo = ((const short8*)Wl)[nt * 64 + lane];
      acc[nt] = __builtin_amdgcn_mfma_f32_16x16x32_bf16(ahi, bhi, acc[nt], 0, 0, 0);
      acc[nt] = __builtin_amdgcn_mfma_f32_16x16x32_bf16(ahi, blo, acc[nt], 0, 0, 0);
      acc[nt] = __builtin_amdgcn_mfma_f32_16x16x32_bf16(alo, bhi, acc[nt], 0, 0, 0);
    }
  }

#pragma unroll
  for (int nt = 0; nt < 16; nt++)
#pragma unroll
    for (int r = 0; r < 4; r++) {
      int m = m0 + quad * 4 + r;
      if (m < N_NODES)
        feat[(size_t)m * 256 + nt * 16 + l15] = __float2bfloat16(acc[nt][r]);
    }
#pragma unroll
  for (int r = 0; r < 4; r++) {
    int m = m0 + quad * 4 + r;
    if (m < N_NODES) {
      float v = acc[16][r];
      if (l15 < 8) el[m * 8 + l15] = v;
      else         er[m * 8 + (l15 - 8)] = v;
    }
  }
}

// ---------------------------------------------------------------------------
// R14 fused aggregate + semantic GEMM (EXACT — best measured: 239us).
// ---------------------------------------------------------------------------
__global__ __launch_bounds__(512) void agg_sem_kernel(
    const int* __restrict__ csr_src, const int* __restrict__ off3,
    const int* __restrict__ deg3,
    const float* __restrict__ el3, const float* __restrict__ er3,
    const __hip_bfloat16* __restrict__ feat3,
    const __hip_bfloat16* __restrict__ Bs_hi, const __hip_bfloat16* __restrict__ Bs_lo,
    const float* __restrict__ bias, float* __restrict__ out) {
  __shared__ __align__(16) short Ahi[16 * A_STR];   // 8448 B
  __shared__ __align__(16) short Alo[16 * A_STR];   // 8448 B
  __shared__ int idxbuf[8 * 128];                   // 4096 B (2 nodes / wave)
  const int t = threadIdx.x;
  const int w = t >> 6, lane = t & 63;
  const int half = lane >> 5;          // 0: even edges, 1: odd edges
  const int l5 = lane & 31;            // channel group: channels 8*l5 .. 8*l5+7
  const int hh = l5 >> 2;              // head of this lane's 8 channels
  const int node_base = blockIdx.x * 16;
  const int l15 = lane & 15, quad = lane >> 4;
  const int nt = w;

  v4f acc = {0.f, 0.f, 0.f, 0.f};

  for (int p = 0; p < NPATH; p++) {
    const int* offp = off3 + p * N_NODES;
    const int* degp = deg3 + p * N_NODES;
    const float* elh = el3 + (size_t)p * N_NODES * 8 + hh;
    const float* erp = er3 + (size_t)p * N_NODES * 8;
    const ushort* fpl = (const ushort*)(feat3 + (size_t)p * N_NODES * 256) + l5 * 8;

    const int node0 = node_base + 2 * w;
    const int nA_deg = degp[node0];
    const int nB_deg = degp[node0 + 1];
    const int* LA = csr_src + offp[node0];
    const int* LB = csr_src + offp[node0 + 1];
    // stage both nodes' edge indices (lane (half,l5) -> edge 2*l5+half)
    {
      int pos = 2 * l5 + half;
      int sb = w * 128 + (half << 5) + l5;
      idxbuf[sb]      = (pos < nA_deg) ? LA[pos] : 0;
      idxbuf[sb + 64] = (pos < nB_deg) ? LB[pos] : 0;
    }

#define LD(S, kk) do {                                                    \
      int2 id_ = *(const int2*)&idxbuf[ib2 + (kk)];                       \
      unsigned ia_ = (unsigned)id_.x, ic_ = (unsigned)id_.y;              \
      x##S##a = elh[ia_ * 8u];                                            \
      x##S##b = elh[ic_ * 8u];                                            \
      f##S##a = *(const uint4*)(fpl + ia_ * 256u);                        \
      f##S##b = *(const uint4*)(fpl + ic_ * 256u);                        \
    } while (0)

#define CN(S, kk) do {                                                    \
      float xx0 = x##S##a + erh;                                          \
      xx0 = fmaxf(xx0, 0.2f * xx0);                                       \
      float e0 = ((kk) < nh) ? __expf(xx0) : 0.f;                         \
      float xx1 = x##S##b + erh;                                          \
      xx1 = fmaxf(xx1, 0.2f * xx1);                                       \
      float e1 = ((kk) + 1 < nh) ? __expf(xx1) : 0.f;                     \
      aD += e0; aD += e1;                                                 \
      f2 e20 = {e0, e0}, e21 = {e1, e1};                                  \
      a0 = __builtin_elementwise_fma(e20, up2(f##S##a.x), a0);            \
      a1 = __builtin_elementwise_fma(e20, up2(f##S##a.y), a1);            \
      a2 = __builtin_elementwise_fma(e20, up2(f##S##a.z), a2);            \
      a3 = __builtin_elementwise_fma(e20, up2(f##S##a.w), a3);            \
      a0 = __builtin_elementwise_fma(e21, up2(f##S##b.x), a0);            \
      a1 = __builtin_elementwise_fma(e21, up2(f##S##b.y), a1);            \
      a2 = __builtin_elementwise_fma(e21, up2(f##S##b.z), a2);            \
      a3 = __builtin_elementwise_fma(e21, up2(f##S##b.w), a3);            \
    } while (0)

    // ---- edge phase: wave w aggregates nodes 2w and 2w+1 ----
#pragma unroll
    for (int i = 0; i < 2; i++) {
      const int node = node0 + i;
      const int n = (i == 0) ? nA_deg : nB_deg;
      const int* lst2 = (i == 0) ? LA : LB;
      const float erh = erp[node * 8 + hh];
      const int ncov = n < 64 ? n : 64;
      const int nh = (ncov - half + 1) >> 1;   // valid edges this half
      const int nmax = (ncov + 1) >> 1;        // uniform loop bound
      const int ib2 = w * 128 + i * 64 + (half << 5);

      f2 a0 = {0.f, 0.f}, a1 = {0.f, 0.f}, a2 = {0.f, 0.f}, a3 = {0.f, 0.f};
      float aD = 0.f;
      uint4 fAa, fAb, fBa, fBb, fCa, fCb;
      float xAa, xAb, xBa, xBb, xCa, xCb;

      if (nmax > 0) LD(A, 0);
      if (nmax > 2) LD(B, 2);
      if (nmax > 4) LD(C, 4);
      for (int k = 0; k < nmax; k += 6) {
        CN(A, k);
        if (k + 6 < nmax) LD(A, k + 6);
        if (k + 2 < nmax) {
          CN(B, k + 2);
          if (k + 8 < nmax) LD(B, k + 8);
          if (k + 4 < nmax) {
            CN(C, k + 4);
            if (k + 10 < nmax) LD(C, k + 10);
          }
        }
      }
      // rare tail: degree > 64 (~0 nodes for Poisson-16 degrees)
      if (n > 64) {
        for (int j = 64; j < n; j += 2) {
          int v = (j + half) < n;
          unsigned su = v ? (unsigned)lst2[j + half] : 0u;
          float x = elh[su * 8u];
          uint4 f = *(const uint4*)(fpl + su * 256u);
          float xx = x + erh;
          xx = fmaxf(xx, 0.2f * xx);
          float e = v ? __expf(xx) : 0.f;
          aD += e;
          f2 e2t = {e, e};
          a0 = __builtin_elementwise_fma(e2t, up2(f.x), a0);
          a1 = __builtin_elementwise_fma(e2t, up2(f.y), a1);
          a2 = __builtin_elementwise_fma(e2t, up2(f.z), a2);
          a3 = __builtin_elementwise_fma(e2t, up2(f.w), a3);
        }
      }

      // combine even/odd halves (lane l <-> lane l+32)
      float aN[8] = {a0.x, a0.y, a1.x, a1.y, a2.x, a2.y, a3.x, a3.y};
#pragma unroll
      for (int k = 0; k < 8; k++) aN[k] += __shfl_xor(aN[k], 32, 64);
      aD += __shfl_xor(aD, 32, 64);

      float inv = (n > 0) ? 1.f / aD : 0.f;
      // ELU + hi/lo bf16 split ONCE, store fragment-ready
      short8 hi8, lo8;
#pragma unroll
      for (int k = 0; k < 8; k++) {
        float r = aN[k] * inv;
        r = r > 0.f ? r : (__expf(r) - 1.f);
        float back, back2;
        hi8[k] = f2bf(r, &back);
        lo8[k] = f2bf(r - back, &back2);
      }
      const int row = 2 * w + i;
      short* dst = half ? Alo : Ahi;
      short8 vv = half ? lo8 : hi8;
      *(short8*)&dst[row * A_STR + l5 * 8] = vv;
    }
#undef LD
#undef CN
    __syncthreads();

    // ---- sem MFMA phase: wave w -> N-tile nt = w; acc accumulates over p ----
    const __hip_bfloat16* bh = Bs_hi + (size_t)p * 32768;
    const __hip_bfloat16* bl = Bs_lo + (size_t)p * 32768;
#pragma unroll
    for (int kc = 0; kc < 8; kc++) {
      short8 ahi = *(const short8*)&Ahi[l15 * A_STR + kc * 32 + quad * 8];
      short8 alo = *(const short8*)&Alo[l15 * A_STR + kc * 32 + quad * 8];
      const int o = ((kc * 8 + nt) * 64 + lane) * 8;
      short8 bhi = *(const short8*)(bh + o);
      short8 blo = *(const short8*)(bl + o);
      acc = __builtin_amdgcn_mfma_f32_16x16x32_bf16(ahi, bhi, acc, 0, 0, 0);
      acc = __builtin_amdgcn_mfma_f32_16x16x32_bf16(ahi, blo, acc, 0, 0, 0);
      acc = __builtin_amdgcn_mfma_f32_16x16x32_bf16(alo, bhi, acc, 0, 0, 0);
    }
    __syncthreads();   // protect LDS before next path overwrites
  }

  const float bv = bias[nt * 16 + l15];
#pragma unroll
  for (int r = 0; r < 4; r++) {
    int m = node_base + quad * 4 + r;
    out[(size_t)m * 128 + nt * 16 + l15] = acc[r] + bv;
  }
}

// ---------------------------------------------------------------------------
extern "C" void kernel_launch(void* const* d_in, const int* in_sizes, int n_in,
                              void* d_out, int out_size, void* d_ws, size_t ws_size,
                              hipStream_t stream) {
  const float* h      = (const float*)d_in[0];
  const int*   ei     = (const int*)d_in[1];
  const float* fc_w   = (const float*)d_in[2];
  const float* attn_l = (const float*)d_in[3];
  const float* attn_r = (const float*)d_in[4];
  const float* sem_w  = (const float*)d_in[5];
  const float* sem_b  = (const float*)d_in[6];
  float* out = (float*)d_out;

  // workspace layout (bytes) — total ~118.4 MB (<=132.8 MB proven safe)
  char* ws = (char*)d_ws;
  __hip_bfloat16* feat3 = (__hip_bfloat16*)ws;                     // 76.8 MB
  float* el3     = (float*)(ws + 76800000);                        // 4.8 MB
  float* er3     = (float*)(ws + 81600000);                        // 4.8 MB
  int*   csr_src = (int*)(ws + 86400000);                          // 9.6 MB
  int2*  ebuf    = (int2*)(ws + 96000000);                         // 19.2 MB
  int*   deg3    = (int*)(ws + 115200000);                         // 0.6 MB
  int*   off3    = (int*)(ws + 115800000);                         // 0.6 MB
  int*   cntmat  = (int*)(ws + 116400000);                         // 602 KB
  int*   posm    = (int*)(ws + 117050000);                         // 602 KB
  int*   btot    = (int*)(ws + 117700000);                         // 2.4 KB
  int*   boff    = (int*)(ws + 117710000);                         // 2.4 KB
  __hip_bfloat16* Wf_hi = (__hip_bfloat16*)(ws + 117800000);       // 3x69632 B
  __hip_bfloat16* Wf_lo = (__hip_bfloat16*)(ws + 118050000);       // 3x69632 B
  __hip_bfloat16* Bs_hi = (__hip_bfloat16*)(ws + 118300000);       // 3x65536 B
  __hip_bfloat16* Bs_lo = (__hip_bfloat16*)(ws + 118550000);       // 3x65536 B

  // --- CSR build (deterministic counting sort) + fused weight prep ---
  blk_count_kernel<<<NCHUNKBLK, 256, 0, stream>>>(ei, cntmat);
  col_scan_kernel<<<NBKT3, 256, 0, stream>>>(cntmat, posm, btot);
  bucket_scan_kernel<<<1, 1024, 0, stream>>>(btot, boff);
  scatter_det_kernel<<<NCHUNKBLK, 256, 0, stream>>>(ei, boff, posm, ebuf);
  bucket_csr_kernel<<<NBKT3, 256, 0, stream>>>(ebuf, boff, btot, off3, deg3, csr_src);
  prep_kernel<<<NPATH * 33, 256, 0, stream>>>(fc_w, attn_l, attn_r, sem_w,
                                              Wf_hi, Wf_lo, Bs_hi, Bs_lo);

  // --- all 3 feat GEMMs in one dispatch (4-wave blocks, LDS weights) ---
  feat_mfma_kernel<<<dim3((N_NODES + 63) / 64, NPATH), 256, 0, stream>>>(
      h, Wf_hi, Wf_lo, feat3, el3, er3);

  // --- fused aggregate + semantic GEMM, all 3 paths in ONE dispatch ---
  agg_sem_kernel<<<N_NODES / 16, 512, 0, stream>>>(
      csr_src, off3, deg3, el3, er3, feat3, Bs_hi, Bs_lo, sem_b, out);
}